// Round 4
// baseline (156.087 us; speedup 1.0000x reference)
//
#include <hip/hip_runtime.h>
#include <cstdint>
#include <cstddef>

namespace {

constexpr int LVL = 16;       // grid levels
constexpr int TSZ = 1 << 16;  // hash table size per level
constexpr uint32_t PRIME_Y = 2654435761u;
constexpr uint32_t PRIME_Z = 805459861u;
constexpr int OUTD = 71;      // 32 hash feats + 39 positional enc
constexpr int PPW = 32;       // points per wave (2 lanes per point)
constexpr int PPB = 128;      // points per block (4 waves)
constexpr int SROWD = 37;     // LDS row stride in dwords (71 cols packed bf16 + pad)

__device__ __forceinline__ float fract1(float v) { return v - floorf(v); }

__device__ __forceinline__ uint32_t pack_bf16(float a, float b) {
    // round-to-nearest-even bf16, packed (a -> lo16, b -> hi16)
    uint32_t ua = __float_as_uint(a), ub = __float_as_uint(b);
    ua = (ua + 0x7FFFu + ((ua >> 16) & 1u)) >> 16;
    ub = (ub + 0x7FFFu + ((ub >> 16) & 1u)) & 0xFFFF0000u;
    return ua | ub;
}

// ---- pre-pass: convert active layer's table f32[2] -> packed bf16 dword ----
__global__ __launch_bounds__(256) void convert_table_kernel(
    const float* __restrict__ tables, const int* __restrict__ layerid,
    uint32_t* __restrict__ tab_bf16)
{
    const float* __restrict__ src = tables + (size_t)layerid[0] * (2u * LVL * (size_t)TSZ);
    const int n_entries = LVL * TSZ;  // 1M entries (2 floats each)
    int i = blockIdx.x * blockDim.x + threadIdx.x;
    const int stride = gridDim.x * blockDim.x;
    for (; i < n_entries; i += stride) {
        const uint32_t lo = __float_as_uint(src[2 * i + 0]);
        const uint32_t hi = __float_as_uint(src[2 * i + 1]);
        tab_bf16[i] = (lo >> 16) | (hi & 0xFFFF0000u);  // truncate, err <= 2^-8 rel
    }
}

__global__ __launch_bounds__(256, 8) void hashgrid_enc_kernel(
    const float* __restrict__ x, const float* __restrict__ t,
    const int* __restrict__ mask, const int* __restrict__ layerid,
    const uint32_t* __restrict__ tab_bf16, const float* __restrict__ bbox,
    float* __restrict__ out, int n)
{
    __shared__ uint32_t lds[4 * PPW * SROWD];   // 18,944 B -> 8 blocks/CU

    const int lane = threadIdx.x & 63;
    const int wave = threadIdx.x >> 6;
    const uint32_t half = (uint32_t)(lane & 1);      // which 4 corners this lane owns
    const int rowbase = blockIdx.x * PPB + wave * PPW;
    const int p = rowbase + (lane >> 1);
    const int i = (p < n) ? p : (n - 1);             // clamp; flush is guarded

    // ---- uniform config ----
    const int m0 = mask[0];
    const int m2 = mask[2];
    const int k0 = m0 ? 0 : 1;
    const int k1 = m2 ? 2 : 1;

    // ---- load point ----
    const float xv0 = x[3 * (size_t)i + 0];
    const float xv1 = x[3 * (size_t)i + 1];
    const float xv2 = x[3 * (size_t)i + 2];
    const float xt0 = (k0 == 0) ? xv0 : xv1;
    const float xt1 = (k1 == 2) ? xv2 : xv1;
    const float xt2 = t[i];

    const float lo0 = bbox[0], lo1 = bbox[1], lo2 = bbox[2];
    const float hi0 = bbox[3], hi1 = bbox[4], hi2 = bbox[5];
    const float u0 = fminf(fmaxf((xt0 - lo0) / (hi0 - lo0), 0.f), 1.f);
    const float u1 = fminf(fmaxf((xt1 - lo1) / (hi1 - lo1), 0.f), 1.f);
    const float u2 = fminf(fmaxf((xt2 - lo2) / (hi2 - lo2), 0.f), 1.f);

    uint32_t* __restrict__ wrowd = lds + (wave * PPW + (lane >> 1)) * SROWD;

    const float res_tab[LVL] = {16.f, 20.f, 25.f, 32.f, 40.f, 50.f, 64.f, 80.f,
                                101.f, 128.f, 161.f, 203.f, 256.f, 322.f, 406.f, 512.f};

    // ---- hash grid: 16 levels, 4 corners/lane, 2-level software pipeline.
    // Per level: shuffle-combine pair partials, pack bf16, write LDS dword l.
    float    pw[2][4];
    uint32_t pv[2][4];

#pragma unroll
    for (int l = 0; l <= LVL; ++l) {
        if (l < LVL) {
            const float r = res_tab[l];
            const float px = u0 * r, py = u1 * r, pz = u2 * r;
            const float f0x = floorf(px), f0y = floorf(py), f0z = floorf(pz);
            const float fx = px - f0x, fy = py - f0y, fz = pz - f0z;
            const uint32_t hx  = (uint32_t)f0x + half;               // prime = 1
            const uint32_t hyA = (uint32_t)f0y * PRIME_Y, hyB = hyA + PRIME_Y;
            const uint32_t hzA = (uint32_t)f0z * PRIME_Z, hzB = hzA + PRIME_Z;
            const float wx = half ? fx : 1.f - fx;
            const uint32_t base = (uint32_t)l * (uint32_t)TSZ;
#pragma unroll
            for (int c = 0; c < 4; ++c) {
                const uint32_t h = hx ^ ((c & 2) ? hyB : hyA) ^ ((c & 1) ? hzB : hzA);
                const uint32_t idx = (h & (uint32_t)(TSZ - 1)) + base;
                pw[l & 1][c] = wx * ((c & 2) ? fy : 1.f - fy) * ((c & 1) ? fz : 1.f - fz);
                pv[l & 1][c] = tab_bf16[idx];
            }
        }
        if (l > 0) {
            const int s = (l - 1) & 1;
            float a0 = 0.f, a1 = 0.f;
#pragma unroll
            for (int c = 0; c < 4; ++c) {
                const uint32_t w = pv[s][c];
                a0 = fmaf(pw[s][c], __uint_as_float(w << 16), a0);
                a1 = fmaf(pw[s][c], __uint_as_float(w & 0xFFFF0000u), a1);
            }
            a0 += __shfl_xor(a0, 1);
            a1 += __shfl_xor(a1, 1);
            if (half == 0) wrowd[l - 1] = pack_bf16(a0, a1);
        }
    }

    // ---- odd lane: positional encoding, packed dword chain (cols 32..70) ----
    if (half == 1) {
        wrowd[16] = pack_bf16(xt0, xt1);                     // cols 32,33
        float s_carry = __builtin_amdgcn_sinf(fract1(xt0 * 0.5f));  // f=0 sin d0
        float c_carry = xt2;                                  // col 34 partner
        int d = 17;
#pragma unroll
        for (int f = 0; f < 6; ++f) {
            const float scale = (f == 0) ? 0.5f : (float)(1 << (f - 1));
            const float r0 = fract1(xt0 * scale);
            const float r1 = fract1(xt1 * scale);
            const float r2 = fract1(xt2 * scale);
            const float s1v = __builtin_amdgcn_sinf(r1);
            const float s2v = __builtin_amdgcn_sinf(r2);
            const float c0v = __builtin_amdgcn_cosf(r0);
            const float c1v = __builtin_amdgcn_cosf(r1);
            const float c2v = __builtin_amdgcn_cosf(r2);
            wrowd[d + 0] = pack_bf16(c_carry, s_carry);       // (prev col, sin d0)
            wrowd[d + 1] = pack_bf16(s1v, s2v);               // sin d1, sin d2
            wrowd[d + 2] = pack_bf16(c0v, c1v);               // cos d0, cos d1
            c_carry = c2v;                                    // cos d2 pairs with next sin d0
            if (f < 5) {
                const float nscale = (float)(1 << f);         // next f's scale = 2^(f)
                s_carry = __builtin_amdgcn_sinf(fract1(xt0 * nscale));
            }
            d += 3;
        }
        wrowd[35] = pack_bf16(c_carry, 0.f);                  // col 70 (+pad)
    }

    __syncthreads();

    // ---- flush: 32 complete rows = 71 full cache lines, line-aligned, f32 out ----
    {
        float* __restrict__ obase = out + (size_t)rowbase * OUTD;
        const uint32_t* __restrict__ wlds = lds + wave * PPW * SROWD;
        const int rows_valid = n - rowbase;
#pragma unroll
        for (int it = 0; it < 36; ++it) {
            const int k = it * 64 + lane;
            if (k < PPW * OUTD) {
                const int r = k / OUTD;
                const int c = k - r * OUTD;
                const uint32_t w = wlds[r * SROWD + (c >> 1)];
                const float v = (c & 1) ? __uint_as_float(w & 0xFFFF0000u)
                                        : __uint_as_float(w << 16);
                if (r < rows_valid)
                    obase[k] = v;
            }
        }
    }
}

} // namespace

extern "C" void kernel_launch(void* const* d_in, const int* in_sizes, int n_in,
                              void* d_out, int out_size, void* d_ws, size_t ws_size,
                              hipStream_t stream) {
    const float* x       = (const float*)d_in[0];
    const float* t       = (const float*)d_in[1];
    const int*   mask    = (const int*)d_in[2];
    const int*   layerid = (const int*)d_in[3];
    const float* tables  = (const float*)d_in[4];
    const float* bbox    = (const float*)d_in[5];
    float*       out     = (float*)d_out;

    const int n = in_sizes[0] / 3;
    const int blocks = (n + PPB - 1) / PPB;

    uint32_t* tab_bf16 = (uint32_t*)d_ws;   // 4 MB packed bf16 table
    hipLaunchKernelGGL(convert_table_kernel, dim3(4096), dim3(256), 0, stream,
                       tables, layerid, tab_bf16);
    hipLaunchKernelGGL(hashgrid_enc_kernel, dim3(blocks), dim3(256), 0, stream,
                       x, t, mask, layerid, tab_bf16, bbox, out, n);
}